// Round 4
// baseline (133.802 us; speedup 1.0000x reference)
//
#include <hip/hip_runtime.h>
#include <stdint.h>

typedef _Float16 half8 __attribute__((ext_vector_type(8)));
typedef _Float16 half4 __attribute__((ext_vector_type(4)));
typedef __fp16   fp16x2 __attribute__((ext_vector_type(2)));
typedef float    floatx4 __attribute__((ext_vector_type(4)));

#define T_LEN 2048
#define CH 64
#define BH 32            // bs * n_heads
#define QTILE 128        // t per block (32 per wave) -> 512 blocks = 2 blocks/CU
#define LDP 72           // prep LDS pad (halves)
#define PTP 72           // Pt row stride (halves)
#define FRAG_BH 131072   // halves per bh per tensor (64*2048)

// ---------------- pass 1: fp32 -> fp16, reorder into MFMA fragment order ----------
// Q pre-scaled by 0.125 * rescale * log2(e) so attention does raw exp2.
// QF/KF[bh][g][ks][lane][8]: g = t(or s)>>4, element = X[c = ks*32+quad*8+j][t = g*16+l15]
// VF[bh][stile64][ct*2+ks][lane][8]: element = V[c = ct*16+l15][s = stile64*64+ks*32+quad*8+j]
__global__ __launch_bounds__(256, 2)
void prep_kernel(const float* __restrict__ qkv, const float* __restrict__ rescale,
                 _Float16* __restrict__ ws)
{
    __shared__ _Float16 Qs[64][LDP];   // [t][c]
    __shared__ _Float16 Ks[64][LDP];   // [s][c]
    __shared__ _Float16 Vs[64][LDP];   // [c][s]

    const int tid  = threadIdx.x;
    const int bh   = blockIdx.y;
    const int tile = blockIdx.x;       // 64-element tile along t/s
    const int x0   = tile * 64;

    const float qscale = 0.125f * 1.4426950408889634f * rescale[0];

    const float* qp = qkv + (size_t)(bh >> 3) * (1536 * T_LEN)
                          + (size_t)(bh & 7) * (192 * T_LEN);
    const float* kp = qp + 64 * T_LEN;
    const float* vp = qp + 128 * T_LEN;

    // Q,K: 4x4 register-block transpose [c][t] -> [t][c]
    {
        const int a4 = (tid & 15) * 4;
        const int c4 = (tid >> 4) * 4;
        float4 rq[4], rk[4];
#pragma unroll
        for (int i = 0; i < 4; ++i) {
            rq[i] = *(const float4*)(qp + (size_t)(c4 + i) * T_LEN + x0 + a4);
            rk[i] = *(const float4*)(kp + (size_t)(c4 + i) * T_LEN + x0 + a4);
        }
#pragma unroll
        for (int j = 0; j < 4; ++j) {
            half4 hq, hk;
#pragma unroll
            for (int i = 0; i < 4; ++i) {
                hq[i] = (_Float16)((&rq[i].x)[j] * qscale);
                hk[i] = (_Float16)((&rk[i].x)[j]);
            }
            *(half4*)&Qs[a4 + j][c4] = hq;
            *(half4*)&Ks[a4 + j][c4] = hk;
        }
        // V natural [c][s]
        const int s4 = (tid & 15) * 4;
        const int cv = tid >> 4;
#pragma unroll
        for (int i = 0; i < 4; ++i) {
            const int c = cv + 16 * i;
            float4 r = *(const float4*)(vp + (size_t)c * T_LEN + x0 + s4);
            half4 h; h[0]=(_Float16)r.x; h[1]=(_Float16)r.y; h[2]=(_Float16)r.z; h[3]=(_Float16)r.w;
            *(half4*)&Vs[c][s4] = h;
        }
    }
    __syncthreads();

    const int lane = tid & 63, wave = tid >> 6;
    const int l15 = lane & 15, quad = lane >> 4;
    _Float16* qf = ws;
    _Float16* kf = ws + (size_t)BH * FRAG_BH;
    _Float16* vf = ws + (size_t)2 * BH * FRAG_BH;

#pragma unroll
    for (int ks = 0; ks < 2; ++ks) {
        half8 hq = *(const half8*)&Qs[wave * 16 + l15][ks * 32 + quad * 8];
        half8 hk = *(const half8*)&Ks[wave * 16 + l15][ks * 32 + quad * 8];
        half8 hv = *(const half8*)&Vs[wave * 16 + l15][ks * 32 + quad * 8];
        const size_t gqk = (((size_t)bh * 128 + tile * 4 + wave) * 2 + ks) * 512 + lane * 8;
        *(half8*)(qf + gqk) = hq;
        *(half8*)(kf + gqk) = hk;
        *(half8*)(vf + (((size_t)bh * 32 + tile) * 8 + wave * 2 + ks) * 512 + lane * 8) = hv;
    }
}

// async global->LDS, 16B per lane: dest = lds_base(uniform) + lane*16
__device__ __forceinline__ void gload16(const _Float16* g, _Float16* l) {
    __builtin_amdgcn_global_load_lds(
        (const __attribute__((address_space(1))) void*)g,
        (__attribute__((address_space(3))) void*)l, 16, 0, 0);
}

// ---------------- pass 2: attention, LDS-staged K/V, register-pipelined ------------
// Round-3 post-mortem: 47.7us identical across round-0 (private VMEM, no barrier)
// and round-3 (LDS staged, 1 barrier/iter) -> not BW-bound at 2 blocks/CU. Pipe
// accounting: MfmaUtil 32% + VALUBusy 29% + DS ~25% ~= 86% -> pipes run
// SEQUENTIALLY (phase-locked waves, serial per-wave chain). The exposed link:
// old order PV(st-1),QK(st),exp(st) leaves the exp/cvt/Pt chain (~450cy) between
// QK(st) and its consumer PV(st) with no MFMA to hide under.
// This round: reorder to QK(st) -> PV(st-1) -> exp(st). The 40 independent MFMAs
// form one cluster; exp (depends only on QK) gets scheduled under the PV stream.
// Pt->ap read moved AFTER the barrier (Pt is per-wave private; per-wave in-order
// DS makes the cross-barrier RAW safe), shortening the pre-barrier tail.
// s_setprio(1/0) wraps the MFMA cluster (T5). Memory structure unchanged
// (staging/XCD swizzle/dbuf: FETCH 12.3MB verified).
__global__ __launch_bounds__(256, 2)
void attn_kernel(const _Float16* __restrict__ ws, float* __restrict__ out)
{
    __shared__ _Float16 Kb[2][4096];      // [buf][8KB tile]
    __shared__ _Float16 Vb[2][4096];
    __shared__ _Float16 Pt[4][32][PTP];   // per wave: [t_rel 32][s_rel 64]

    const int tid  = threadIdx.x;
    const int wave = tid >> 6;
    const int lane = tid & 63;
    const int l15  = lane & 15;
    const int quad = lane >> 4;

    // XCD-aware decode: all 16 t-tiles of one bh on ONE XCD (4 bh x 512KB = 2MB/XCD L2)
    const int bid  = blockIdx.x;        // 0..511
    const int xcd  = bid & 7;
    const int slot = bid >> 3;          // 0..63
    const int bh   = (slot >> 4) * 8 + xcd;
    const int tile = slot & 15;
    const int t0   = tile * QTILE;

    const _Float16* qf = ws;
    const _Float16* kf = ws + (size_t)BH * FRAG_BH;
    const _Float16* vf = ws + (size_t)2 * BH * FRAG_BH;
    float* op = out + (size_t)bh * (CH * T_LEN);

    const _Float16* ktile = kf + (size_t)bh * FRAG_BH;   // + st*4096 per tile
    const _Float16* vtile = vf + (size_t)bh * FRAG_BH;

    // stage tile st into buf: 16KB split over 4 waves, 4 async insts/wave
    auto stage = [&](int st, int buf) {
        const _Float16* kg = ktile + (size_t)st * 4096 + wave * 1024 + lane * 8;
        const _Float16* vg = vtile + (size_t)st * 4096 + wave * 1024 + lane * 8;
        _Float16* kl = &Kb[buf][wave * 1024];
        _Float16* vl = &Vb[buf][wave * 1024];
        gload16(kg,       kl);
        gload16(kg + 512, kl + 512);
        gload16(vg,       vl);
        gload16(vg + 512, vl + 512);
    };

    // Q fragments: persistent (Q pre-scaled in prep); 32 t/wave = 2 t-groups
    half8 bq[2][2];
#pragma unroll
    for (int tb = 0; tb < 2; ++tb)
#pragma unroll
        for (int ks = 0; ks < 2; ++ks)
            bq[tb][ks] = *(const half8*)(qf +
                (((size_t)bh * 128 + tile * 8 + wave * 2 + tb) * 2 + ks) * 512 + lane * 8);

    const floatx4 fzero = {0.f, 0.f, 0.f, 0.f};
    floatx4 oacc[2][4];                 // [tb][ctile]
#pragma unroll
    for (int tb = 0; tb < 2; ++tb)
#pragma unroll
        for (int ct = 0; ct < 4; ++ct) oacc[tb][ct] = fzero;
    floatx4 lacc[2] = {fzero, fzero};   // row sums via ones-MFMA

    half8 bones;
#pragma unroll
    for (int i = 0; i < 8; ++i) bones[i] = (_Float16)1.0f;

    half8 ak[4][2];        // K(st) fragments (from LDS)
    half8 bv[4][2];        // V(st-1) at loop top
    half8 ap[2][2];        // P(st-1) at loop top
    floatx4 sacc[4][2];    // QK(st) logits, live QK -> exp

    auto read_ak = [&](int buf) {
#pragma unroll
        for (int mt = 0; mt < 4; ++mt)
#pragma unroll
            for (int ks = 0; ks < 2; ++ks)
                ak[mt][ks] = *(const half8*)&Kb[buf][(mt * 2 + ks) * 512 + lane * 8];
    };
    auto read_bv = [&](int buf) {
#pragma unroll
        for (int ct = 0; ct < 4; ++ct)
#pragma unroll
            for (int ks = 0; ks < 2; ++ks)
                bv[ct][ks] = *(const half8*)&Vb[buf][(ct * 2 + ks) * 512 + lane * 8];
    };
    auto read_ap = [&]() {
#pragma unroll
        for (int tb = 0; tb < 2; ++tb)
#pragma unroll
            for (int ks = 0; ks < 2; ++ks)
                ap[tb][ks] = *(const half8*)&Pt[wave][tb * 16 + l15][ks * 32 + quad * 8];
    };

    // QK(st): 16 independent MFMAs into sacc
    auto do_qk = [&]() {
#pragma unroll
        for (int mt = 0; mt < 4; ++mt)
#pragma unroll
            for (int tb = 0; tb < 2; ++tb) sacc[mt][tb] = fzero;
#pragma unroll
        for (int mt = 0; mt < 4; ++mt)
#pragma unroll
            for (int tb = 0; tb < 2; ++tb)
#pragma unroll
                for (int ks = 0; ks < 2; ++ks)
                    sacc[mt][tb] = __builtin_amdgcn_mfma_f32_16x16x32_f16(
                        ak[mt][ks], bq[tb][ks], sacc[mt][tb], 0, 0, 0);
    };

    // PV(st-1): 24 independent MFMAs from ap, bv
    auto do_pv = [&]() {
#pragma unroll
        for (int tb = 0; tb < 2; ++tb)
#pragma unroll
            for (int ks = 0; ks < 2; ++ks)
                lacc[tb] = __builtin_amdgcn_mfma_f32_16x16x32_f16(ap[tb][ks], bones, lacc[tb], 0, 0, 0);
#pragma unroll
        for (int tb = 0; tb < 2; ++tb)
#pragma unroll
            for (int ct = 0; ct < 4; ++ct)
#pragma unroll
                for (int ks = 0; ks < 2; ++ks)
                    oacc[tb][ct] = __builtin_amdgcn_mfma_f32_16x16x32_f16(
                        ap[tb][ks], bv[ct][ks], oacc[tb][ct], 0, 0, 0);
    };

    // exp(st): sacc -> exp2 -> f16 pack -> Pt (per-wave private; ap read is later,
    // after the barrier -- per-wave in-order DS makes the RAW safe)
    auto do_exp = [&]() {
#pragma unroll
        for (int mt = 0; mt < 4; ++mt)
#pragma unroll
            for (int tb = 0; tb < 2; ++tb) {
                fp16x2 p01 = __builtin_amdgcn_cvt_pkrtz(
                    __builtin_amdgcn_exp2f(sacc[mt][tb][0]),
                    __builtin_amdgcn_exp2f(sacc[mt][tb][1]));
                fp16x2 p23 = __builtin_amdgcn_cvt_pkrtz(
                    __builtin_amdgcn_exp2f(sacc[mt][tb][2]),
                    __builtin_amdgcn_exp2f(sacc[mt][tb][3]));
                half4 ph;
                ph[0] = (_Float16)p01[0]; ph[1] = (_Float16)p01[1];
                ph[2] = (_Float16)p23[0]; ph[3] = (_Float16)p23[1];
                *(half4*)&Pt[wave][tb * 16 + l15][mt * 16 + quad * 4] = ph;
            }
    };

    // ---- prologue
    stage(0, 0);
    __syncthreads();                  // tile 0 in buf 0
    read_ak(0);
    stage(1, 1);                      // full iteration to land
    __builtin_amdgcn_s_setprio(1);
    do_qk();                          // QK(0)
    __builtin_amdgcn_s_setprio(0);
    read_bv(0);                       // V(0)
    do_exp();                         // P(0) -> Pt
    __syncthreads();                  // tile 1 landed; all buf-0 reads drained
    read_ak(1);                       // K(1)
    read_ap();                        // P(0) -> ap

    // ---- main loop: iter st does QK(st), PV(st-1), exp(st)
#pragma unroll 2
    for (int st = 1; st < 32; ++st) {
        const int cur = st & 1;
        if (st < 31) stage(st + 1, cur ^ 1);   // overwrites tile st-1 (reads drained)

        __builtin_amdgcn_s_setprio(1);
        do_qk();                      // QK(st): ak ready
        do_pv();                      // PV(st-1): ap, bv ready; independent of QK
        __builtin_amdgcn_s_setprio(0);

        read_bv(cur);                 // V(st) for next iteration's PV
        do_exp();                     // exp(st) -> Pt; scheduler hides under PV MFMAs

        __syncthreads();              // tile st+1 in buf[cur^1]; lgkm drained
        if (st < 31) read_ak(cur ^ 1);   // K(st+1)
        read_ap();                    // P(st) -> ap
    }

    // ---- epilogue: PV(31)
    do_pv();

    // normalize + store: col = c = ct*16 + l15, rows t = t0 + wave*32 + tb*16 + quad*4 + r
#pragma unroll
    for (int tb = 0; tb < 2; ++tb) {
        float linv[4];
#pragma unroll
        for (int r = 0; r < 4; ++r) linv[r] = 1.0f / lacc[tb][r];
#pragma unroll
        for (int ct = 0; ct < 4; ++ct) {
            const int c = ct * 16 + l15;
            const int t = t0 + wave * 32 + tb * 16 + quad * 4;
            float4 o;
#pragma unroll
            for (int r = 0; r < 4; ++r)
                (&o.x)[r] = oacc[tb][ct][r] * linv[r];
            *(float4*)(op + (size_t)c * T_LEN + t) = o;
        }
    }
}

extern "C" void kernel_launch(void* const* d_in, const int* in_sizes, int n_in,
                              void* d_out, int out_size, void* d_ws, size_t ws_size,
                              hipStream_t stream) {
    const float* qkv     = (const float*)d_in[0];
    const float* rescale = (const float*)d_in[1];
    float* out = (float*)d_out;
    _Float16* ws = (_Float16*)d_ws;   // needs 3*32*131072*2 B = 25.2 MB

    prep_kernel<<<dim3(32, BH), dim3(256), 0, stream>>>(qkv, rescale, ws);
    attn_kernel<<<dim3(T_LEN / QTILE * BH), dim3(256), 0, stream>>>(ws, out);
}